// Round 8
// baseline (2292.871 us; speedup 1.0000x reference)
//
#include <hip/hip_runtime.h>
#include <hip/hip_bf16.h>
#include <math.h>

// Problem dims (fixed)
#define NN 16384
#define BB 32
#define HH 15
#define KK 25
#define GG 64
#define CC 6
#define EE (NN * 32)
#define NG ((size_t)NN * GG)
#define PSTRIDE 4096      // partials stride (max blocks of any final variant)

typedef unsigned int u32;
typedef unsigned short u16;
typedef __attribute__((ext_vector_type(8))) short bf16x8;
typedef __attribute__((ext_vector_type(4))) float f32x4;
typedef __attribute__((ext_vector_type(4))) u32 u32x4;

// ---------------- CSR build ----------------

__global__ void init_counts(int* __restrict__ cnt) {
    int t = blockIdx.x * 256 + threadIdx.x;
    if (t < NN) cnt[t] = 0;
}

__global__ void hist_kernel(const int* __restrict__ src, int* __restrict__ cnt) {
    int e = blockIdx.x * 256 + threadIdx.x;
    if (e < EE) atomicAdd(&cnt[src[e]], 1);
}

__global__ __launch_bounds__(1024) void scan_kernel(const int* __restrict__ cnt,
                                                    int* __restrict__ rowptr,
                                                    int* __restrict__ cursor) {
    __shared__ int sums[1024];
    int t = threadIdx.x;
    int base = t * 16;
    int local[16];
    int s = 0;
#pragma unroll
    for (int i = 0; i < 16; ++i) { local[i] = s; s += cnt[base + i]; }
    sums[t] = s;
    __syncthreads();
    for (int off = 1; off < 1024; off <<= 1) {
        int v = (t >= off) ? sums[t - off] : 0;
        __syncthreads();
        sums[t] += v;
        __syncthreads();
    }
    int prefix = (t == 0) ? 0 : sums[t - 1];
#pragma unroll
    for (int i = 0; i < 16; ++i) {
        int rp = prefix + local[i];
        rowptr[base + i] = rp;
        cursor[base + i] = rp;
    }
    if (t == 1023) rowptr[NN] = sums[1023];
}

__global__ void scatter_kernel(const int* __restrict__ src, const int* __restrict__ dst,
                               const float* __restrict__ w, int* __restrict__ cursor,
                               int* __restrict__ col, float* __restrict__ wgt) {
    int e = blockIdx.x * 256 + threadIdx.x;
    if (e < EE) {
        int pos = atomicAdd(&cursor[src[e]], 1);
        col[pos] = dst[e];
        wgt[pos] = w[e];
    }
}

// ---------------- helpers ----------------

__device__ __forceinline__ u16 f2bf(float f) {
    __hip_bfloat16 b = __float2bfloat16(f);            // RNE
    return *reinterpret_cast<u16*>(&b);
}
__device__ __forceinline__ float bflo(u32 d) { return __uint_as_float(d << 16); }
__device__ __forceinline__ float bfhi(u32 d) { return __uint_as_float(d & 0xffff0000u); }

// ---------------- W -> bf16, transposed for MFMA B-frags: WbfT[g][416] ----------------

__global__ void prep_wbf(const float* __restrict__ W, u16* __restrict__ WbfT) {
    int t = blockIdx.x * 256 + threadIdx.x;   // t over 64*416
    if (t >= GG * 416) return;
    int g = t / 416;
    int f = t % 416;
    int k = f >> 4;
    int h = f & 15;
    float v = (k < KK && h < HH) ? W[(k * HH + h) * GG + g] : 0.f;
    WbfT[(size_t)g * 416 + f] = f2bf(v);
}

// ---------------- transpose chunk: packed bf16 rows [n][bb][h-pairs] ----------------

template<int BCH>
__global__ void transpose_bf(const float* __restrict__ x, u32* __restrict__ X0, int b0) {
    constexpr int CW = BCH * 8;
    int t = blockIdx.x * 256 + threadIdx.x;     // t = n*CW + j
    int n = t / CW;
    int j = t % CW;
    int bb = j >> 3;
    int h0 = (j & 7) * 2;
    const float* xb = x + ((size_t)(b0 + bb) * NN + n) * HH;
    float lo = xb[h0];
    float hi = (h0 + 1 < HH) ? xb[h0 + 1] : 0.f;
    X0[t] = (u32)f2bf(lo) | ((u32)f2bf(hi) << 16);
}

// ---------------- SPMM quad-gather (BCH==4): 8 edges per dwordx4 load ----------------
// wave per row (4/block). lane = (grp = edge slot 0..7, m8 = dword-quad 0..7).
// One global_load_dwordx4 gathers 8 edges x 16B = 1KB. 16 edges (2 loads) per iter.

__global__ __launch_bounds__(256) void spmm_bf4(
    const int* __restrict__ rowptr, const int* __restrict__ col, const float* __restrict__ wgt,
    const u32* __restrict__ Xin, const u32* __restrict__ Xprev, u32* __restrict__ Xout,
    float alpha, float beta)
{
    int sub  = threadIdx.x >> 6;
    int lane = threadIdx.x & 63;
    int n = blockIdx.x * 4 + sub;
    int e0 = rowptr[n], e1 = rowptr[n + 1];
    int grp = lane >> 3;        // edge slot 0..7
    int m8  = lane & 7;         // dword-quad within 32-dword row

    float al[4] = {0.f,0.f,0.f,0.f}, ah[4] = {0.f,0.f,0.f,0.f};
    float bl[4] = {0.f,0.f,0.f,0.f}, bh[4] = {0.f,0.f,0.f,0.f};

    for (int base = e0; base < e1; base += 64) {
        int cnt = e1 - base;
        if (cnt > 64) cnt = 64;
        int cv = 0; float wv = 0.f;
        if (lane < cnt) { cv = col[base + lane]; wv = wgt[base + lane]; }
        int j = 0;
        for (; j + 16 <= cnt; j += 16) {
            int   iA = __shfl(cv, j + grp);
            float wA = __shfl(wv, j + grp);
            int   iB = __shfl(cv, j + 8 + grp);
            float wB = __shfl(wv, j + 8 + grp);
            u32x4 dA = *(const u32x4*)(Xin + (size_t)iA * 32 + m8 * 4);
            u32x4 dB = *(const u32x4*)(Xin + (size_t)iB * 32 + m8 * 4);
#pragma unroll
            for (int i = 0; i < 4; ++i) {
                al[i] = fmaf(wA, bflo(dA[i]), al[i]);
                ah[i] = fmaf(wA, bfhi(dA[i]), ah[i]);
                bl[i] = fmaf(wB, bflo(dB[i]), bl[i]);
                bh[i] = fmaf(wB, bfhi(dB[i]), bh[i]);
            }
        }
        for (; j < cnt; j += 8) {
            int   iA = __shfl(cv, j + grp);
            float wA = __shfl(wv, j + grp);
            u32x4 dA = *(const u32x4*)(Xin + (size_t)iA * 32 + m8 * 4);
#pragma unroll
            for (int i = 0; i < 4; ++i) {
                al[i] = fmaf(wA, bflo(dA[i]), al[i]);
                ah[i] = fmaf(wA, bfhi(dA[i]), ah[i]);
            }
        }
    }

#pragma unroll
    for (int i = 0; i < 4; ++i) { al[i] += bl[i]; ah[i] += bh[i]; }
#pragma unroll
    for (int off = 8; off < 64; off <<= 1)
#pragma unroll
        for (int i = 0; i < 4; ++i) {
            al[i] += __shfl_xor(al[i], off);
            ah[i] += __shfl_xor(ah[i], off);
        }

    if (grp == 0) {
        size_t o = (size_t)n * 32 + (size_t)m8 * 4;
        u32x4 dp = {0,0,0,0};
        if (beta != 0.f) dp = *(const u32x4*)(Xprev + o);
        u32x4 r;
#pragma unroll
        for (int i = 0; i < 4; ++i) {
            float rl = alpha * al[i];
            float rh = alpha * ah[i];
            if (beta != 0.f) {
                rl = fmaf(beta, bflo(dp[i]), rl);
                rh = fmaf(beta, bfhi(dp[i]), rh);
            }
            r[i] = (u32)f2bf(rl) | ((u32)f2bf(rh) << 16);
        }
        *(u32x4*)(Xout + o) = r;
    }
}

// ---------------- SPMM scalar fallback (BCH<4) ----------------

template<int BCH>
__global__ __launch_bounds__(256) void spmm_bf(
    const int* __restrict__ rowptr, const int* __restrict__ col, const float* __restrict__ wgt,
    const u32* __restrict__ Xin, const u32* __restrict__ Xprev, u32* __restrict__ Xout,
    float alpha, float beta)
{
    constexpr int C  = BCH * 16;      // bf16 cols per row
    int sub  = threadIdx.x >> 6;
    int lane = threadIdx.x & 63;
    int n = blockIdx.x * 4 + sub;
    int e0 = rowptr[n], e1 = rowptr[n + 1];

    int c = lane;
    const u16* XinU  = (const u16*)Xin;
    const u16* XprevU= (const u16*)Xprev;
    u16* XoutU = (u16*)Xout;
    float a0=0.f,a1=0.f,a2=0.f,a3=0.f;
    bool act = (c < C);
    for (int base = e0; base < e1; base += 64) {
        int cnt = e1 - base;
        if (cnt > 64) cnt = 64;
        int cv = 0; float wv = 0.f;
        if (lane < cnt) { cv = col[base + lane]; wv = wgt[base + lane]; }
        int j = 0;
        for (; j + 4 <= cnt; j += 4) {
            int i0 = __builtin_amdgcn_readlane(cv, j);
            int i1 = __builtin_amdgcn_readlane(cv, j + 1);
            int i2 = __builtin_amdgcn_readlane(cv, j + 2);
            int i3 = __builtin_amdgcn_readlane(cv, j + 3);
            float w0 = __int_as_float(__builtin_amdgcn_readlane(__float_as_int(wv), j));
            float w1 = __int_as_float(__builtin_amdgcn_readlane(__float_as_int(wv), j + 1));
            float w2 = __int_as_float(__builtin_amdgcn_readlane(__float_as_int(wv), j + 2));
            float w3 = __int_as_float(__builtin_amdgcn_readlane(__float_as_int(wv), j + 3));
            if (act) {
                float x0 = __uint_as_float((u32)XinU[(size_t)i0 * C + c] << 16);
                float x1 = __uint_as_float((u32)XinU[(size_t)i1 * C + c] << 16);
                float x2 = __uint_as_float((u32)XinU[(size_t)i2 * C + c] << 16);
                float x3 = __uint_as_float((u32)XinU[(size_t)i3 * C + c] << 16);
                a0 = fmaf(w0, x0, a0);
                a1 = fmaf(w1, x1, a1);
                a2 = fmaf(w2, x2, a2);
                a3 = fmaf(w3, x3, a3);
            }
        }
        for (; j < cnt; ++j) {
            int i0 = __builtin_amdgcn_readlane(cv, j);
            float w0 = __int_as_float(__builtin_amdgcn_readlane(__float_as_int(wv), j));
            if (act) a0 = fmaf(w0, __uint_as_float((u32)XinU[(size_t)i0 * C + c] << 16), a0);
        }
    }
    if (act) {
        float r = alpha * ((a0 + a1) + (a2 + a3));
        size_t o = (size_t)n * C + c;
        if (beta != 0.f)
            r = fmaf(beta, __uint_as_float((u32)XprevU[o] << 16), r);
        XoutU[o] = f2bf(r);
    }
}

// ---------------- final4: MFMA contraction (BCH == 8 or 4) ----------------
// GEMM: OUT[r=(n,bb), g] = sum_f X[r][f] * W[f][g], K=400 pad 416, 13 steps of 32.
// Per slice, row r occupies 8 dwords at offset r*8 for both BCH=8 and 4.

template<int BCH>
__global__ __launch_bounds__(256) void final4_t(
    const u32* __restrict__ Xall, const u16* __restrict__ WbfT,
    const float* __restrict__ b_conv, const float* __restrict__ Wfc,
    float* __restrict__ partials, int b0)
{
    constexpr int SLICE_DW = NN * BCH * 8;
    __shared__ float sred[4][BCH * CC];
    int tid  = threadIdx.x;
    int wid  = tid >> 6;
    int lane = tid & 63;
    int q = lane >> 4;      // k-chunk quarter
    int m = lane & 15;
    int r0 = (blockIdx.x * 4 + wid) * 16;   // M-tile base row; r = n*BCH + bb
    int r  = r0 + m;

    f32x4 acc0 = {0.f,0.f,0.f,0.f}, acc1 = {0.f,0.f,0.f,0.f};
    f32x4 acc2 = {0.f,0.f,0.f,0.f}, acc3 = {0.f,0.f,0.f,0.f};

    const u32* abase = Xall + (size_t)r * 8 + (size_t)(q & 1) * 4;
    const u16* bbase = WbfT + (size_t)m * 416 + q * 8;

#pragma unroll
    for (int s = 0; s < 13; ++s) {
        int ks = 2 * s + (q >> 1);
        bf16x8 af = {0,0,0,0,0,0,0,0};
        if (s < 12 || q < 2)
            af = *(const bf16x8*)(abase + (size_t)ks * SLICE_DW);
        bf16x8 bf0 = *(const bf16x8*)(bbase + (size_t)0 * 16 * 416 + s * 32);
        bf16x8 bf1 = *(const bf16x8*)(bbase + (size_t)1 * 16 * 416 + s * 32);
        bf16x8 bf2 = *(const bf16x8*)(bbase + (size_t)2 * 16 * 416 + s * 32);
        bf16x8 bf3 = *(const bf16x8*)(bbase + (size_t)3 * 16 * 416 + s * 32);
        acc0 = __builtin_amdgcn_mfma_f32_16x16x32_bf16(af, bf0, acc0, 0, 0, 0);
        acc1 = __builtin_amdgcn_mfma_f32_16x16x32_bf16(af, bf1, acc1, 0, 0, 0);
        acc2 = __builtin_amdgcn_mfma_f32_16x16x32_bf16(af, bf2, acc2, 0, 0, 0);
        acc3 = __builtin_amdgcn_mfma_f32_16x16x32_bf16(af, bf3, acc3, 0, 0, 0);
    }

    // C/D layout: acc{gt}[i] -> row rr = r0 + q*4 + i, col g = gt*16 + m
    float part[4][CC];
#pragma unroll
    for (int i = 0; i < 4; ++i)
#pragma unroll
        for (int c = 0; c < CC; ++c) part[i][c] = 0.f;

#pragma unroll
    for (int gt = 0; gt < 4; ++gt) {
        f32x4 a = (gt == 0) ? acc0 : (gt == 1) ? acc1 : (gt == 2) ? acc2 : acc3;
        float bias = b_conv[gt * 16 + m];
#pragma unroll
        for (int i = 0; i < 4; ++i) {
            int rr = r0 + q * 4 + i;
            int nrow = rr / BCH;
            float hv = fmaxf(a[i] + bias, 0.f);
#pragma unroll
            for (int c = 0; c < CC; ++c)
                part[i][c] = fmaf(hv,
                    Wfc[(size_t)c * NG + (size_t)nrow * GG + gt * 16 + m], part[i][c]);
        }
    }

    // reduce over m (g dim)
#pragma unroll
    for (int o = 1; o < 16; o <<= 1)
#pragma unroll
        for (int i = 0; i < 4; ++i)
#pragma unroll
            for (int c = 0; c < CC; ++c)
                part[i][c] += __shfl_xor(part[i][c], o);

    if constexpr (BCH == 8) {
        // pair nodes: q ^ 2 (same bb = q*4+i mod 8)
#pragma unroll
        for (int i = 0; i < 4; ++i)
#pragma unroll
            for (int c = 0; c < CC; ++c)
                part[i][c] += __shfl_xor(part[i][c], 32);
        if (m == 0 && q < 2) {
#pragma unroll
            for (int i = 0; i < 4; ++i)
#pragma unroll
                for (int c = 0; c < CC; ++c)
                    sred[wid][(q * 4 + i) * CC + c] = part[i][c];
        }
    } else {
        // BCH == 4: all q are different nodes with bb = i; sum over q
#pragma unroll
        for (int o = 16; o < 64; o <<= 1)
#pragma unroll
            for (int i = 0; i < 4; ++i)
#pragma unroll
                for (int c = 0; c < CC; ++c)
                    part[i][c] += __shfl_xor(part[i][c], o);
        if (lane == 0) {
#pragma unroll
            for (int i = 0; i < 4; ++i)
#pragma unroll
                for (int c = 0; c < CC; ++c)
                    sred[wid][i * CC + c] = part[i][c];
        }
    }
    __syncthreads();
    if (tid < BCH * CC) {
        float s4 = sred[0][tid] + sred[1][tid] + sred[2][tid] + sred[3][tid];
        int bb = tid / CC;
        int c  = tid % CC;
        partials[((size_t)(b0 + bb) * CC + c) * PSTRIDE + blockIdx.x] = s4;
    }
}

// ---------------- final3 (fallback for BCH<4) ----------------

template<int BCH>
__global__ __launch_bounds__(256) void final3_t(
    const u32* __restrict__ Xall, const float* __restrict__ W,
    const float* __restrict__ b_conv, const float* __restrict__ Wfc,
    float* __restrict__ partials, int b0)
{
    constexpr int CW = BCH * 8;
    __shared__ float sred[4][BCH * CC];
    int g   = threadIdx.x & 63;
    int nlu = __builtin_amdgcn_readfirstlane((int)threadIdx.x) >> 6;
    int n   = blockIdx.x * 4 + nlu;

    float acc[BCH];
#pragma unroll
    for (int bb = 0; bb < BCH; ++bb) acc[bb] = 0.f;

    for (int k = 0; k < KK; ++k) {
        const u32* __restrict__ xrow = Xall + ((size_t)k * NN + n) * CW;
        const float* __restrict__ Wk = W + k * (HH * GG);
        float wreg[HH];
#pragma unroll
        for (int h = 0; h < HH; ++h) wreg[h] = Wk[h * GG + g];
#pragma unroll
        for (int bb = 0; bb < BCH; ++bb) {
            float a = acc[bb];
#pragma unroll
            for (int p = 0; p < 8; ++p) {
                u32 d = xrow[bb * 8 + p];
                a = fmaf(bflo(d), wreg[2 * p], a);
                if (p < 7) a = fmaf(bfhi(d), wreg[2 * p + 1], a);
            }
            acc[bb] = a;
        }
    }

    float bias = b_conv[g];
    float wv[CC];
#pragma unroll
    for (int c = 0; c < CC; ++c)
        wv[c] = Wfc[(size_t)c * NG + (size_t)n * GG + g];

#pragma unroll
    for (int bb = 0; bb < BCH; ++bb) {
        float hv = fmaxf(acc[bb] + bias, 0.f);
#pragma unroll
        for (int c = 0; c < CC; ++c) {
            float s = hv * wv[c];
#pragma unroll
            for (int off = 1; off < 64; off <<= 1) s += __shfl_xor(s, off);
            if (g == 0) sred[nlu][bb * CC + c] = s;
        }
    }
    __syncthreads();
    if (threadIdx.x < BCH * CC) {
        float s = sred[0][threadIdx.x] + sred[1][threadIdx.x]
                + sred[2][threadIdx.x] + sred[3][threadIdx.x];
        int bb = threadIdx.x / CC;
        int c  = threadIdx.x % CC;
        partials[((size_t)(b0 + bb) * CC + c) * PSTRIDE + blockIdx.x] = s;
    }
}

// ---------------- partials -> logits ----------------

__global__ __launch_bounds__(256) void reduce_logits(const float* __restrict__ partials,
                                                     float* __restrict__ logits, int nblk) {
    int idx = blockIdx.x;   // b*CC + c
    const float* p = partials + (size_t)idx * PSTRIDE;
    float s = 0.f;
    for (int i = threadIdx.x; i < nblk; i += 256) s += p[i];
#pragma unroll
    for (int off = 1; off < 64; off <<= 1) s += __shfl_xor(s, off);
    __shared__ float sr[4];
    if ((threadIdx.x & 63) == 0) sr[threadIdx.x >> 6] = s;
    __syncthreads();
    if (threadIdx.x == 0) logits[idx] = sr[0] + sr[1] + sr[2] + sr[3];
}

// ---------------- log_softmax ----------------

__global__ void lsm_kernel(const float* __restrict__ logits, const float* __restrict__ b_fc,
                           float* __restrict__ out) {
    int b = threadIdx.x;
    if (b >= BB) return;
    float v[CC];
    float m = -1e30f;
#pragma unroll
    for (int c = 0; c < CC; ++c) {
        v[c] = logits[b * CC + c] + b_fc[c];
        m = fmaxf(m, v[c]);
    }
    float s = 0.f;
#pragma unroll
    for (int c = 0; c < CC; ++c) s += expf(v[c] - m);
    float ls = m + logf(s);
#pragma unroll
    for (int c = 0; c < CC; ++c) out[b * CC + c] = v[c] - ls;
}

__global__ void sentinel_kernel(float* __restrict__ out) {
    int t = threadIdx.x;
    if (t < BB * CC) out[t] = -12345.f;
}

// ---------------- per-tier pass driver ----------------

template<int BCH>
static void run_passes(const float* x, const float* W, const u16* WbfT,
                       const float* bconv, const float* Wfc,
                       const int* rowptr, const int* col, const float* wgt,
                       u32* Xall, float* partials, hipStream_t stream)
{
    constexpr int CW = BCH * 8;
    const size_t slice = (size_t)NN * CW;   // dwords per slice

    for (int p = 0; p < BB / BCH; ++p) {
        int b0 = p * BCH;
        transpose_bf<BCH><<<(NN * CW) / 256, 256, 0, stream>>>(x, Xall, b0);
        if constexpr (BCH == 4) {
            spmm_bf4<<<NN / 4, 256, 0, stream>>>(
                rowptr, col, wgt, Xall, Xall, Xall + slice, 1.f, 0.f);
            for (int k = 2; k < KK; ++k) {
                spmm_bf4<<<NN / 4, 256, 0, stream>>>(
                    rowptr, col, wgt,
                    Xall + (size_t)(k - 1) * slice,
                    Xall + (size_t)(k - 2) * slice,
                    Xall + (size_t)k * slice, 2.f, -1.f);
            }
            final4_t<4><<<NN * 4 / 64, 256, 0, stream>>>(Xall, WbfT, bconv, Wfc, partials, b0);
        } else {
            spmm_bf<BCH><<<NN / 4, 256, 0, stream>>>(
                rowptr, col, wgt, Xall, Xall, Xall + slice, 1.f, 0.f);
            for (int k = 2; k < KK; ++k) {
                spmm_bf<BCH><<<NN / 4, 256, 0, stream>>>(
                    rowptr, col, wgt,
                    Xall + (size_t)(k - 1) * slice,
                    Xall + (size_t)(k - 2) * slice,
                    Xall + (size_t)k * slice, 2.f, -1.f);
            }
            final3_t<BCH><<<NN / 4, 256, 0, stream>>>(Xall, W, bconv, Wfc, partials, b0);
        }
    }
}

// ---------------- launch ----------------

extern "C" void kernel_launch(void* const* d_in, const int* in_sizes, int n_in,
                              void* d_out, int out_size, void* d_ws, size_t ws_size,
                              hipStream_t stream) {
    const float* x     = (const float*)d_in[0];
    const float* ew    = (const float*)d_in[1];
    const float* W     = (const float*)d_in[2];
    const float* bconv = (const float*)d_in[3];
    const float* Wfc   = (const float*)d_in[4];
    const float* bfc   = (const float*)d_in[5];
    const int*   esrc  = (const int*)d_in[6];
    const int*   edst  = (const int*)d_in[7];
    float* out = (float*)d_out;

    char* ws = (char*)d_ws;
    size_t off = 0;
    auto alloc = [&](size_t bytes) -> void* {
        void* p = (void*)(ws + off);
        off = (off + bytes + 255) & ~(size_t)255;
        return p;
    };
    int*   rowptr   = (int*)  alloc((size_t)(NN + 1) * 4);
    int*   cursor   = (int*)  alloc((size_t)NN * 4);
    int*   cnt      = (int*)  alloc((size_t)NN * 4);
    int*   col      = (int*)  alloc((size_t)EE * 4);
    float* wgt      = (float*)alloc((size_t)EE * 4);
    float* logits   = (float*)alloc(256 * 4);
    u16*   WbfT     = (u16*)  alloc((size_t)GG * 416 * 2);
    float* partials = (float*)alloc((size_t)BB * CC * PSTRIDE * 4);
    size_t fixed = off;

    int BCH = 0;
    for (int b = 4; b >= 1; b >>= 1) {
        size_t need = fixed + (size_t)KK * NN * (size_t)b * 16 * 2;   // bf16 slices
        if (need <= ws_size) { BCH = b; break; }
    }
    if (BCH == 0) {
        sentinel_kernel<<<1, 256, 0, stream>>>(out);
        return;
    }
    u32* Xall = (u32*)(ws + fixed);

    init_counts<<<(NN + 255) / 256, 256, 0, stream>>>(cnt);
    hist_kernel<<<(EE + 255) / 256, 256, 0, stream>>>(esrc, cnt);
    scan_kernel<<<1, 1024, 0, stream>>>(cnt, rowptr, cursor);
    scatter_kernel<<<(EE + 255) / 256, 256, 0, stream>>>(esrc, edst, ew, cursor, col, wgt);
    prep_wbf<<<(GG * 416 + 255) / 256, 256, 0, stream>>>(W, WbfT);

    switch (BCH) {
        case 4:  run_passes<4>(x, W, WbfT, bconv, Wfc, rowptr, col, wgt, Xall, partials, stream); break;
        case 2:  run_passes<2>(x, W, WbfT, bconv, Wfc, rowptr, col, wgt, Xall, partials, stream); break;
        default: run_passes<1>(x, W, WbfT, bconv, Wfc, rowptr, col, wgt, Xall, partials, stream); break;
    }

    int nblk = (BCH == 4) ? (NN * 4 / 64) : (NN / 4);
    reduce_logits<<<BB * CC, 256, 0, stream>>>(partials, logits, nblk);
    lsm_kernel<<<1, 64, 0, stream>>>(logits, bfc, out);
}

// Round 9
// 1938.438 us; speedup vs baseline: 1.1828x; 1.1828x over previous
//
#include <hip/hip_runtime.h>
#include <hip/hip_bf16.h>
#include <math.h>

// Problem dims (fixed)
#define NN 16384
#define BB 32
#define HH 15
#define KK 25
#define GG 64
#define CC 6
#define EE (NN * 32)
#define NG ((size_t)NN * GG)
#define PSTRIDE 4096      // partials stride (max blocks of any final variant)

typedef unsigned int u32;
typedef unsigned short u16;
typedef __attribute__((ext_vector_type(8))) short bf16x8;
typedef __attribute__((ext_vector_type(4))) float f32x4;
typedef __attribute__((ext_vector_type(4))) u32 u32x4;

// ---------------- CSR build ----------------

__global__ void init_counts(int* __restrict__ cnt) {
    int t = blockIdx.x * 256 + threadIdx.x;
    if (t < NN) cnt[t] = 0;
}

__global__ void hist_kernel(const int* __restrict__ src, int* __restrict__ cnt) {
    int e = blockIdx.x * 256 + threadIdx.x;
    if (e < EE) atomicAdd(&cnt[src[e]], 1);
}

__global__ __launch_bounds__(1024) void scan_kernel(const int* __restrict__ cnt,
                                                    int* __restrict__ rowptr,
                                                    int* __restrict__ cursor) {
    __shared__ int sums[1024];
    int t = threadIdx.x;
    int base = t * 16;
    int local[16];
    int s = 0;
#pragma unroll
    for (int i = 0; i < 16; ++i) { local[i] = s; s += cnt[base + i]; }
    sums[t] = s;
    __syncthreads();
    for (int off = 1; off < 1024; off <<= 1) {
        int v = (t >= off) ? sums[t - off] : 0;
        __syncthreads();
        sums[t] += v;
        __syncthreads();
    }
    int prefix = (t == 0) ? 0 : sums[t - 1];
#pragma unroll
    for (int i = 0; i < 16; ++i) {
        int rp = prefix + local[i];
        rowptr[base + i] = rp;
        cursor[base + i] = rp;
    }
    if (t == 1023) rowptr[NN] = sums[1023];
}

__global__ void scatter_kernel(const int* __restrict__ src, const int* __restrict__ dst,
                               const float* __restrict__ w, int* __restrict__ cursor,
                               int* __restrict__ col, float* __restrict__ wgt) {
    int e = blockIdx.x * 256 + threadIdx.x;
    if (e < EE) {
        int pos = atomicAdd(&cursor[src[e]], 1);
        col[pos] = dst[e];
        wgt[pos] = w[e];
    }
}

// ---------------- helpers ----------------

__device__ __forceinline__ u16 f2bf(float f) {
    __hip_bfloat16 b = __float2bfloat16(f);            // RNE
    return *reinterpret_cast<u16*>(&b);
}
__device__ __forceinline__ float bflo(u32 d) { return __uint_as_float(d << 16); }
__device__ __forceinline__ float bfhi(u32 d) { return __uint_as_float(d & 0xffff0000u); }

// ---------------- W -> bf16, transposed for MFMA B-frags: WbfT[g][416] ----------------

__global__ void prep_wbf(const float* __restrict__ W, u16* __restrict__ WbfT) {
    int t = blockIdx.x * 256 + threadIdx.x;   // t over 64*416
    if (t >= GG * 416) return;
    int g = t / 416;
    int f = t % 416;
    int k = f >> 4;
    int h = f & 15;
    float v = (k < KK && h < HH) ? W[(k * HH + h) * GG + g] : 0.f;
    WbfT[(size_t)g * 416 + f] = f2bf(v);
}

// ---------------- transpose chunk: packed bf16 rows [n][bb][h-pairs] ----------------

template<int BCH>
__global__ void transpose_bf(const float* __restrict__ x, u32* __restrict__ X0, int b0) {
    constexpr int CW = BCH * 8;
    int t = blockIdx.x * 256 + threadIdx.x;     // t = n*CW + j
    int n = t / CW;
    int j = t % CW;
    int bb = j >> 3;
    int h0 = (j & 7) * 2;
    const float* xb = x + ((size_t)(b0 + bb) * NN + n) * HH;
    float lo = xb[h0];
    float hi = (h0 + 1 < HH) ? xb[h0 + 1] : 0.f;
    X0[t] = (u32)f2bf(lo) | ((u32)f2bf(hi) << 16);
}

// ---------------- SPMM quad-gather (BCH==8), 4-deep load pipeline ----------------
// wave per row; lane = (grp = edge slot 0..3, m16 = dword-quad 0..15).
// Per iteration: 16 edges via 4 independent dwordx4 gathers in flight.

__global__ __launch_bounds__(256) void spmm_bf8(
    const int* __restrict__ rowptr, const int* __restrict__ col, const float* __restrict__ wgt,
    const u32* __restrict__ Xin, const u32* __restrict__ Xprev, u32* __restrict__ Xout,
    float alpha, float beta)
{
    int sub  = threadIdx.x >> 6;
    int lane = threadIdx.x & 63;
    int n = blockIdx.x * 4 + sub;
    int e0 = rowptr[n], e1 = rowptr[n + 1];
    int grp = lane >> 4;        // edge slot
    int m16 = lane & 15;        // dword-quad within row

    float al[4] = {0.f,0.f,0.f,0.f}, ah[4] = {0.f,0.f,0.f,0.f};
    float bl[4] = {0.f,0.f,0.f,0.f}, bh[4] = {0.f,0.f,0.f,0.f};
    float cl[4] = {0.f,0.f,0.f,0.f}, ch[4] = {0.f,0.f,0.f,0.f};
    float dl[4] = {0.f,0.f,0.f,0.f}, dh[4] = {0.f,0.f,0.f,0.f};

    for (int base = e0; base < e1; base += 64) {
        int cnt = e1 - base;
        if (cnt > 64) cnt = 64;
        int cv = 0; float wv = 0.f;
        if (lane < cnt) { cv = col[base + lane]; wv = wgt[base + lane]; }
        int j = 0;
        for (; j + 16 <= cnt; j += 16) {
            int   iA = __shfl(cv, j + grp);
            float wA = __shfl(wv, j + grp);
            int   iB = __shfl(cv, j + 4 + grp);
            float wB = __shfl(wv, j + 4 + grp);
            int   iC = __shfl(cv, j + 8 + grp);
            float wC = __shfl(wv, j + 8 + grp);
            int   iD = __shfl(cv, j + 12 + grp);
            float wD = __shfl(wv, j + 12 + grp);
            u32x4 dA = *(const u32x4*)(Xin + (size_t)iA * 64 + m16 * 4);
            u32x4 dB = *(const u32x4*)(Xin + (size_t)iB * 64 + m16 * 4);
            u32x4 dC = *(const u32x4*)(Xin + (size_t)iC * 64 + m16 * 4);
            u32x4 dD = *(const u32x4*)(Xin + (size_t)iD * 64 + m16 * 4);
#pragma unroll
            for (int i = 0; i < 4; ++i) {
                al[i] = fmaf(wA, bflo(dA[i]), al[i]);
                ah[i] = fmaf(wA, bfhi(dA[i]), ah[i]);
                bl[i] = fmaf(wB, bflo(dB[i]), bl[i]);
                bh[i] = fmaf(wB, bfhi(dB[i]), bh[i]);
                cl[i] = fmaf(wC, bflo(dC[i]), cl[i]);
                ch[i] = fmaf(wC, bfhi(dC[i]), ch[i]);
                dl[i] = fmaf(wD, bflo(dD[i]), dl[i]);
                dh[i] = fmaf(wD, bfhi(dD[i]), dh[i]);
            }
        }
        for (; j < cnt; j += 4) {
            int   iA = __shfl(cv, j + grp);
            float wA = __shfl(wv, j + grp);
            u32x4 dA = *(const u32x4*)(Xin + (size_t)iA * 64 + m16 * 4);
#pragma unroll
            for (int i = 0; i < 4; ++i) {
                al[i] = fmaf(wA, bflo(dA[i]), al[i]);
                ah[i] = fmaf(wA, bfhi(dA[i]), ah[i]);
            }
        }
    }

#pragma unroll
    for (int i = 0; i < 4; ++i) {
        al[i] = (al[i] + bl[i]) + (cl[i] + dl[i]);
        ah[i] = (ah[i] + bh[i]) + (ch[i] + dh[i]);
    }
#pragma unroll
    for (int off = 16; off < 64; off <<= 1)
#pragma unroll
        for (int i = 0; i < 4; ++i) {
            al[i] += __shfl_xor(al[i], off);
            ah[i] += __shfl_xor(ah[i], off);
        }

    if (grp == 0) {
        size_t o = (size_t)n * 64 + (size_t)m16 * 4;
        u32x4 dp = {0,0,0,0};
        if (beta != 0.f) dp = *(const u32x4*)(Xprev + o);
        u32x4 r;
#pragma unroll
        for (int i = 0; i < 4; ++i) {
            float rl = alpha * al[i];
            float rh = alpha * ah[i];
            if (beta != 0.f) {
                rl = fmaf(beta, bflo(dp[i]), rl);
                rh = fmaf(beta, bfhi(dp[i]), rh);
            }
            r[i] = (u32)f2bf(rl) | ((u32)f2bf(rh) << 16);
        }
        *(u32x4*)(Xout + o) = r;
    }
}

// ---------------- SPMM quad-gather (BCH==4): 8 edges per dwordx4 load ----------------

__global__ __launch_bounds__(256) void spmm_bf4(
    const int* __restrict__ rowptr, const int* __restrict__ col, const float* __restrict__ wgt,
    const u32* __restrict__ Xin, const u32* __restrict__ Xprev, u32* __restrict__ Xout,
    float alpha, float beta)
{
    int sub  = threadIdx.x >> 6;
    int lane = threadIdx.x & 63;
    int n = blockIdx.x * 4 + sub;
    int e0 = rowptr[n], e1 = rowptr[n + 1];
    int grp = lane >> 3;        // edge slot 0..7
    int m8  = lane & 7;         // dword-quad within 32-dword row

    float al[4] = {0.f,0.f,0.f,0.f}, ah[4] = {0.f,0.f,0.f,0.f};
    float bl[4] = {0.f,0.f,0.f,0.f}, bh[4] = {0.f,0.f,0.f,0.f};

    for (int base = e0; base < e1; base += 64) {
        int cnt = e1 - base;
        if (cnt > 64) cnt = 64;
        int cv = 0; float wv = 0.f;
        if (lane < cnt) { cv = col[base + lane]; wv = wgt[base + lane]; }
        int j = 0;
        for (; j + 16 <= cnt; j += 16) {
            int   iA = __shfl(cv, j + grp);
            float wA = __shfl(wv, j + grp);
            int   iB = __shfl(cv, j + 8 + grp);
            float wB = __shfl(wv, j + 8 + grp);
            u32x4 dA = *(const u32x4*)(Xin + (size_t)iA * 32 + m8 * 4);
            u32x4 dB = *(const u32x4*)(Xin + (size_t)iB * 32 + m8 * 4);
#pragma unroll
            for (int i = 0; i < 4; ++i) {
                al[i] = fmaf(wA, bflo(dA[i]), al[i]);
                ah[i] = fmaf(wA, bfhi(dA[i]), ah[i]);
                bl[i] = fmaf(wB, bflo(dB[i]), bl[i]);
                bh[i] = fmaf(wB, bfhi(dB[i]), bh[i]);
            }
        }
        for (; j < cnt; j += 8) {
            int   iA = __shfl(cv, j + grp);
            float wA = __shfl(wv, j + grp);
            u32x4 dA = *(const u32x4*)(Xin + (size_t)iA * 32 + m8 * 4);
#pragma unroll
            for (int i = 0; i < 4; ++i) {
                al[i] = fmaf(wA, bflo(dA[i]), al[i]);
                ah[i] = fmaf(wA, bfhi(dA[i]), ah[i]);
            }
        }
    }

#pragma unroll
    for (int i = 0; i < 4; ++i) { al[i] += bl[i]; ah[i] += bh[i]; }
#pragma unroll
    for (int off = 8; off < 64; off <<= 1)
#pragma unroll
        for (int i = 0; i < 4; ++i) {
            al[i] += __shfl_xor(al[i], off);
            ah[i] += __shfl_xor(ah[i], off);
        }

    if (grp == 0) {
        size_t o = (size_t)n * 32 + (size_t)m8 * 4;
        u32x4 dp = {0,0,0,0};
        if (beta != 0.f) dp = *(const u32x4*)(Xprev + o);
        u32x4 r;
#pragma unroll
        for (int i = 0; i < 4; ++i) {
            float rl = alpha * al[i];
            float rh = alpha * ah[i];
            if (beta != 0.f) {
                rl = fmaf(beta, bflo(dp[i]), rl);
                rh = fmaf(beta, bfhi(dp[i]), rh);
            }
            r[i] = (u32)f2bf(rl) | ((u32)f2bf(rh) << 16);
        }
        *(u32x4*)(Xout + o) = r;
    }
}

// ---------------- SPMM scalar fallback (BCH<4) ----------------

template<int BCH>
__global__ __launch_bounds__(256) void spmm_bf(
    const int* __restrict__ rowptr, const int* __restrict__ col, const float* __restrict__ wgt,
    const u32* __restrict__ Xin, const u32* __restrict__ Xprev, u32* __restrict__ Xout,
    float alpha, float beta)
{
    constexpr int C  = BCH * 16;      // bf16 cols per row
    int sub  = threadIdx.x >> 6;
    int lane = threadIdx.x & 63;
    int n = blockIdx.x * 4 + sub;
    int e0 = rowptr[n], e1 = rowptr[n + 1];

    int c = lane;
    const u16* XinU  = (const u16*)Xin;
    const u16* XprevU= (const u16*)Xprev;
    u16* XoutU = (u16*)Xout;
    float a0=0.f,a1=0.f,a2=0.f,a3=0.f;
    bool act = (c < C);
    for (int base = e0; base < e1; base += 64) {
        int cnt = e1 - base;
        if (cnt > 64) cnt = 64;
        int cv = 0; float wv = 0.f;
        if (lane < cnt) { cv = col[base + lane]; wv = wgt[base + lane]; }
        int j = 0;
        for (; j + 4 <= cnt; j += 4) {
            int i0 = __builtin_amdgcn_readlane(cv, j);
            int i1 = __builtin_amdgcn_readlane(cv, j + 1);
            int i2 = __builtin_amdgcn_readlane(cv, j + 2);
            int i3 = __builtin_amdgcn_readlane(cv, j + 3);
            float w0 = __int_as_float(__builtin_amdgcn_readlane(__float_as_int(wv), j));
            float w1 = __int_as_float(__builtin_amdgcn_readlane(__float_as_int(wv), j + 1));
            float w2 = __int_as_float(__builtin_amdgcn_readlane(__float_as_int(wv), j + 2));
            float w3 = __int_as_float(__builtin_amdgcn_readlane(__float_as_int(wv), j + 3));
            if (act) {
                float x0 = __uint_as_float((u32)XinU[(size_t)i0 * C + c] << 16);
                float x1 = __uint_as_float((u32)XinU[(size_t)i1 * C + c] << 16);
                float x2 = __uint_as_float((u32)XinU[(size_t)i2 * C + c] << 16);
                float x3 = __uint_as_float((u32)XinU[(size_t)i3 * C + c] << 16);
                a0 = fmaf(w0, x0, a0);
                a1 = fmaf(w1, x1, a1);
                a2 = fmaf(w2, x2, a2);
                a3 = fmaf(w3, x3, a3);
            }
        }
        for (; j < cnt; ++j) {
            int i0 = __builtin_amdgcn_readlane(cv, j);
            float w0 = __int_as_float(__builtin_amdgcn_readlane(__float_as_int(wv), j));
            if (act) a0 = fmaf(w0, __uint_as_float((u32)XinU[(size_t)i0 * C + c] << 16), a0);
        }
    }
    if (act) {
        float r = alpha * ((a0 + a1) + (a2 + a3));
        size_t o = (size_t)n * C + c;
        if (beta != 0.f)
            r = fmaf(beta, __uint_as_float((u32)XprevU[o] << 16), r);
        XoutU[o] = f2bf(r);
    }
}

// ---------------- final4: MFMA contraction (BCH == 8 or 4) ----------------

template<int BCH>
__global__ __launch_bounds__(256) void final4_t(
    const u32* __restrict__ Xall, const u16* __restrict__ WbfT,
    const float* __restrict__ b_conv, const float* __restrict__ Wfc,
    float* __restrict__ partials, int b0)
{
    constexpr int SLICE_DW = NN * BCH * 8;
    __shared__ float sred[4][BCH * CC];
    int tid  = threadIdx.x;
    int wid  = tid >> 6;
    int lane = tid & 63;
    int q = lane >> 4;      // k-chunk quarter
    int m = lane & 15;
    int r0 = (blockIdx.x * 4 + wid) * 16;   // M-tile base row; r = n*BCH + bb
    int r  = r0 + m;

    f32x4 acc0 = {0.f,0.f,0.f,0.f}, acc1 = {0.f,0.f,0.f,0.f};
    f32x4 acc2 = {0.f,0.f,0.f,0.f}, acc3 = {0.f,0.f,0.f,0.f};

    const u32* abase = Xall + (size_t)r * 8 + (size_t)(q & 1) * 4;
    const u16* bbase = WbfT + (size_t)m * 416 + q * 8;

#pragma unroll
    for (int s = 0; s < 13; ++s) {
        int ks = 2 * s + (q >> 1);
        bf16x8 af = {0,0,0,0,0,0,0,0};
        if (s < 12 || q < 2)
            af = *(const bf16x8*)(abase + (size_t)ks * SLICE_DW);
        bf16x8 bf0 = *(const bf16x8*)(bbase + (size_t)0 * 16 * 416 + s * 32);
        bf16x8 bf1 = *(const bf16x8*)(bbase + (size_t)1 * 16 * 416 + s * 32);
        bf16x8 bf2 = *(const bf16x8*)(bbase + (size_t)2 * 16 * 416 + s * 32);
        bf16x8 bf3 = *(const bf16x8*)(bbase + (size_t)3 * 16 * 416 + s * 32);
        acc0 = __builtin_amdgcn_mfma_f32_16x16x32_bf16(af, bf0, acc0, 0, 0, 0);
        acc1 = __builtin_amdgcn_mfma_f32_16x16x32_bf16(af, bf1, acc1, 0, 0, 0);
        acc2 = __builtin_amdgcn_mfma_f32_16x16x32_bf16(af, bf2, acc2, 0, 0, 0);
        acc3 = __builtin_amdgcn_mfma_f32_16x16x32_bf16(af, bf3, acc3, 0, 0, 0);
    }

    // C/D layout: acc{gt}[i] -> row rr = r0 + q*4 + i, col g = gt*16 + m
    float part[4][CC];
#pragma unroll
    for (int i = 0; i < 4; ++i)
#pragma unroll
        for (int c = 0; c < CC; ++c) part[i][c] = 0.f;

#pragma unroll
    for (int gt = 0; gt < 4; ++gt) {
        f32x4 a = (gt == 0) ? acc0 : (gt == 1) ? acc1 : (gt == 2) ? acc2 : acc3;
        float bias = b_conv[gt * 16 + m];
#pragma unroll
        for (int i = 0; i < 4; ++i) {
            int rr = r0 + q * 4 + i;
            int nrow = rr / BCH;
            float hv = fmaxf(a[i] + bias, 0.f);
#pragma unroll
            for (int c = 0; c < CC; ++c)
                part[i][c] = fmaf(hv,
                    Wfc[(size_t)c * NG + (size_t)nrow * GG + gt * 16 + m], part[i][c]);
        }
    }

    // reduce over m (g dim)
#pragma unroll
    for (int o = 1; o < 16; o <<= 1)
#pragma unroll
        for (int i = 0; i < 4; ++i)
#pragma unroll
            for (int c = 0; c < CC; ++c)
                part[i][c] += __shfl_xor(part[i][c], o);

    if constexpr (BCH == 8) {
#pragma unroll
        for (int i = 0; i < 4; ++i)
#pragma unroll
            for (int c = 0; c < CC; ++c)
                part[i][c] += __shfl_xor(part[i][c], 32);
        if (m == 0 && q < 2) {
#pragma unroll
            for (int i = 0; i < 4; ++i)
#pragma unroll
                for (int c = 0; c < CC; ++c)
                    sred[wid][(q * 4 + i) * CC + c] = part[i][c];
        }
    } else {
#pragma unroll
        for (int o = 16; o < 64; o <<= 1)
#pragma unroll
            for (int i = 0; i < 4; ++i)
#pragma unroll
                for (int c = 0; c < CC; ++c)
                    part[i][c] += __shfl_xor(part[i][c], o);
        if (lane == 0) {
#pragma unroll
            for (int i = 0; i < 4; ++i)
#pragma unroll
                for (int c = 0; c < CC; ++c)
                    sred[wid][i * CC + c] = part[i][c];
        }
    }
    __syncthreads();
    if (tid < BCH * CC) {
        float s4 = sred[0][tid] + sred[1][tid] + sred[2][tid] + sred[3][tid];
        int bb = tid / CC;
        int c  = tid % CC;
        partials[((size_t)(b0 + bb) * CC + c) * PSTRIDE + blockIdx.x] = s4;
    }
}

// ---------------- final3 (fallback for BCH<4) ----------------

template<int BCH>
__global__ __launch_bounds__(256) void final3_t(
    const u32* __restrict__ Xall, const float* __restrict__ W,
    const float* __restrict__ b_conv, const float* __restrict__ Wfc,
    float* __restrict__ partials, int b0)
{
    constexpr int CW = BCH * 8;
    __shared__ float sred[4][BCH * CC];
    int g   = threadIdx.x & 63;
    int nlu = __builtin_amdgcn_readfirstlane((int)threadIdx.x) >> 6;
    int n   = blockIdx.x * 4 + nlu;

    float acc[BCH];
#pragma unroll
    for (int bb = 0; bb < BCH; ++bb) acc[bb] = 0.f;

    for (int k = 0; k < KK; ++k) {
        const u32* __restrict__ xrow = Xall + ((size_t)k * NN + n) * CW;
        const float* __restrict__ Wk = W + k * (HH * GG);
        float wreg[HH];
#pragma unroll
        for (int h = 0; h < HH; ++h) wreg[h] = Wk[h * GG + g];
#pragma unroll
        for (int bb = 0; bb < BCH; ++bb) {
            float a = acc[bb];
#pragma unroll
            for (int p = 0; p < 8; ++p) {
                u32 d = xrow[bb * 8 + p];
                a = fmaf(bflo(d), wreg[2 * p], a);
                if (p < 7) a = fmaf(bfhi(d), wreg[2 * p + 1], a);
            }
            acc[bb] = a;
        }
    }

    float bias = b_conv[g];
    float wv[CC];
#pragma unroll
    for (int c = 0; c < CC; ++c)
        wv[c] = Wfc[(size_t)c * NG + (size_t)n * GG + g];

#pragma unroll
    for (int bb = 0; bb < BCH; ++bb) {
        float hv = fmaxf(acc[bb] + bias, 0.f);
#pragma unroll
        for (int c = 0; c < CC; ++c) {
            float s = hv * wv[c];
#pragma unroll
            for (int off = 1; off < 64; off <<= 1) s += __shfl_xor(s, off);
            if (g == 0) sred[nlu][bb * CC + c] = s;
        }
    }
    __syncthreads();
    if (threadIdx.x < BCH * CC) {
        float s = sred[0][threadIdx.x] + sred[1][threadIdx.x]
                + sred[2][threadIdx.x] + sred[3][threadIdx.x];
        int bb = threadIdx.x / CC;
        int c  = threadIdx.x % CC;
        partials[((size_t)(b0 + bb) * CC + c) * PSTRIDE + blockIdx.x] = s;
    }
}

// ---------------- partials -> logits ----------------

__global__ __launch_bounds__(256) void reduce_logits(const float* __restrict__ partials,
                                                     float* __restrict__ logits, int nblk) {
    int idx = blockIdx.x;   // b*CC + c
    const float* p = partials + (size_t)idx * PSTRIDE;
    float s = 0.f;
    for (int i = threadIdx.x; i < nblk; i += 256) s += p[i];
#pragma unroll
    for (int off = 1; off < 64; off <<= 1) s += __shfl_xor(s, off);
    __shared__ float sr[4];
    if ((threadIdx.x & 63) == 0) sr[threadIdx.x >> 6] = s;
    __syncthreads();
    if (threadIdx.x == 0) logits[idx] = sr[0] + sr[1] + sr[2] + sr[3];
}

// ---------------- log_softmax ----------------

__global__ void lsm_kernel(const float* __restrict__ logits, const float* __restrict__ b_fc,
                           float* __restrict__ out) {
    int b = threadIdx.x;
    if (b >= BB) return;
    float v[CC];
    float m = -1e30f;
#pragma unroll
    for (int c = 0; c < CC; ++c) {
        v[c] = logits[b * CC + c] + b_fc[c];
        m = fmaxf(m, v[c]);
    }
    float s = 0.f;
#pragma unroll
    for (int c = 0; c < CC; ++c) s += expf(v[c] - m);
    float ls = m + logf(s);
#pragma unroll
    for (int c = 0; c < CC; ++c) out[b * CC + c] = v[c] - ls;
}

__global__ void sentinel_kernel(float* __restrict__ out) {
    int t = threadIdx.x;
    if (t < BB * CC) out[t] = -12345.f;
}

// ---------------- per-tier pass driver ----------------

template<int BCH>
static void run_passes(const float* x, const float* W, const u16* WbfT,
                       const float* bconv, const float* Wfc,
                       const int* rowptr, const int* col, const float* wgt,
                       u32* Xall, float* partials, hipStream_t stream)
{
    constexpr int CW = BCH * 8;
    const size_t slice = (size_t)NN * CW;   // dwords per slice

    for (int p = 0; p < BB / BCH; ++p) {
        int b0 = p * BCH;
        transpose_bf<BCH><<<(NN * CW) / 256, 256, 0, stream>>>(x, Xall, b0);
        if constexpr (BCH == 8) {
            spmm_bf8<<<NN / 4, 256, 0, stream>>>(
                rowptr, col, wgt, Xall, Xall, Xall + slice, 1.f, 0.f);
            for (int k = 2; k < KK; ++k) {
                spmm_bf8<<<NN / 4, 256, 0, stream>>>(
                    rowptr, col, wgt,
                    Xall + (size_t)(k - 1) * slice,
                    Xall + (size_t)(k - 2) * slice,
                    Xall + (size_t)k * slice, 2.f, -1.f);
            }
            final4_t<8><<<NN * 8 / 64, 256, 0, stream>>>(Xall, WbfT, bconv, Wfc, partials, b0);
        } else if constexpr (BCH == 4) {
            spmm_bf4<<<NN / 4, 256, 0, stream>>>(
                rowptr, col, wgt, Xall, Xall, Xall + slice, 1.f, 0.f);
            for (int k = 2; k < KK; ++k) {
                spmm_bf4<<<NN / 4, 256, 0, stream>>>(
                    rowptr, col, wgt,
                    Xall + (size_t)(k - 1) * slice,
                    Xall + (size_t)(k - 2) * slice,
                    Xall + (size_t)k * slice, 2.f, -1.f);
            }
            final4_t<4><<<NN * 4 / 64, 256, 0, stream>>>(Xall, WbfT, bconv, Wfc, partials, b0);
        } else {
            spmm_bf<BCH><<<NN / 4, 256, 0, stream>>>(
                rowptr, col, wgt, Xall, Xall, Xall + slice, 1.f, 0.f);
            for (int k = 2; k < KK; ++k) {
                spmm_bf<BCH><<<NN / 4, 256, 0, stream>>>(
                    rowptr, col, wgt,
                    Xall + (size_t)(k - 1) * slice,
                    Xall + (size_t)(k - 2) * slice,
                    Xall + (size_t)k * slice, 2.f, -1.f);
            }
            final3_t<BCH><<<NN / 4, 256, 0, stream>>>(Xall, W, bconv, Wfc, partials, b0);
        }
    }
}

// ---------------- launch ----------------

extern "C" void kernel_launch(void* const* d_in, const int* in_sizes, int n_in,
                              void* d_out, int out_size, void* d_ws, size_t ws_size,
                              hipStream_t stream) {
    const float* x     = (const float*)d_in[0];
    const float* ew    = (const float*)d_in[1];
    const float* W     = (const float*)d_in[2];
    const float* bconv = (const float*)d_in[3];
    const float* Wfc   = (const float*)d_in[4];
    const float* bfc   = (const float*)d_in[5];
    const int*   esrc  = (const int*)d_in[6];
    const int*   edst  = (const int*)d_in[7];
    float* out = (float*)d_out;

    char* ws = (char*)d_ws;
    size_t off = 0;
    auto alloc = [&](size_t bytes) -> void* {
        void* p = (void*)(ws + off);
        off = (off + bytes + 255) & ~(size_t)255;
        return p;
    };
    int*   rowptr   = (int*)  alloc((size_t)(NN + 1) * 4);
    int*   cursor   = (int*)  alloc((size_t)NN * 4);
    int*   cnt      = (int*)  alloc((size_t)NN * 4);
    int*   col      = (int*)  alloc((size_t)EE * 4);
    float* wgt      = (float*)alloc((size_t)EE * 4);
    float* logits   = (float*)alloc(256 * 4);
    u16*   WbfT     = (u16*)  alloc((size_t)GG * 416 * 2);
    float* partials = (float*)alloc((size_t)BB * CC * PSTRIDE * 4);
    size_t fixed = off;

    int BCH = 0;
    for (int b = 8; b >= 1; b >>= 1) {
        size_t need = fixed + (size_t)KK * NN * (size_t)b * 16 * 2;   // bf16 slices
        if (need <= ws_size) { BCH = b; break; }
    }
    if (BCH == 0) {
        sentinel_kernel<<<1, 256, 0, stream>>>(out);
        return;
    }
    u32* Xall = (u32*)(ws + fixed);

    init_counts<<<(NN + 255) / 256, 256, 0, stream>>>(cnt);
    hist_kernel<<<(EE + 255) / 256, 256, 0, stream>>>(esrc, cnt);
    scan_kernel<<<1, 1024, 0, stream>>>(cnt, rowptr, cursor);
    scatter_kernel<<<(EE + 255) / 256, 256, 0, stream>>>(esrc, edst, ew, cursor, col, wgt);
    prep_wbf<<<(GG * 416 + 255) / 256, 256, 0, stream>>>(W, WbfT);

    switch (BCH) {
        case 8:  run_passes<8>(x, W, WbfT, bconv, Wfc, rowptr, col, wgt, Xall, partials, stream); break;
        case 4:  run_passes<4>(x, W, WbfT, bconv, Wfc, rowptr, col, wgt, Xall, partials, stream); break;
        case 2:  run_passes<2>(x, W, WbfT, bconv, Wfc, rowptr, col, wgt, Xall, partials, stream); break;
        default: run_passes<1>(x, W, WbfT, bconv, Wfc, rowptr, col, wgt, Xall, partials, stream); break;
    }

    int nblk = (BCH == 8) ? 2048 : (BCH == 4) ? 1024 : (NN / 4);
    reduce_logits<<<BB * CC, 256, 0, stream>>>(partials, logits, nblk);
    lsm_kernel<<<1, 64, 0, stream>>>(logits, bfc, out);
}

// Round 10
// 1650.348 us; speedup vs baseline: 1.3893x; 1.1746x over previous
//
#include <hip/hip_runtime.h>
#include <hip/hip_bf16.h>
#include <math.h>

// Problem dims (fixed)
#define NN 16384
#define BB 32
#define HH 15
#define KK 25
#define GG 64
#define CC 6
#define EE (NN * 32)
#define NG ((size_t)NN * GG)
#define PSTRIDE 8192      // partials stride (max blocks of any final variant)

typedef unsigned int u32;
typedef unsigned short u16;
typedef __attribute__((ext_vector_type(8))) short bf16x8;
typedef __attribute__((ext_vector_type(4))) float f32x4;
typedef __attribute__((ext_vector_type(4))) u32 u32x4;

// ---------------- CSR build ----------------

__global__ void init_counts(int* __restrict__ cnt) {
    int t = blockIdx.x * 256 + threadIdx.x;
    if (t < NN) cnt[t] = 0;
}

__global__ void hist_kernel(const int* __restrict__ src, int* __restrict__ cnt) {
    int e = blockIdx.x * 256 + threadIdx.x;
    if (e < EE) atomicAdd(&cnt[src[e]], 1);
}

__global__ __launch_bounds__(1024) void scan_kernel(const int* __restrict__ cnt,
                                                    int* __restrict__ rowptr,
                                                    int* __restrict__ cursor) {
    __shared__ int sums[1024];
    int t = threadIdx.x;
    int base = t * 16;
    int local[16];
    int s = 0;
#pragma unroll
    for (int i = 0; i < 16; ++i) { local[i] = s; s += cnt[base + i]; }
    sums[t] = s;
    __syncthreads();
    for (int off = 1; off < 1024; off <<= 1) {
        int v = (t >= off) ? sums[t - off] : 0;
        __syncthreads();
        sums[t] += v;
        __syncthreads();
    }
    int prefix = (t == 0) ? 0 : sums[t - 1];
#pragma unroll
    for (int i = 0; i < 16; ++i) {
        int rp = prefix + local[i];
        rowptr[base + i] = rp;
        cursor[base + i] = rp;
    }
    if (t == 1023) rowptr[NN] = sums[1023];
}

__global__ void scatter_kernel(const int* __restrict__ src, const int* __restrict__ dst,
                               const float* __restrict__ w, int* __restrict__ cursor,
                               int* __restrict__ col, float* __restrict__ wgt) {
    int e = blockIdx.x * 256 + threadIdx.x;
    if (e < EE) {
        int pos = atomicAdd(&cursor[src[e]], 1);
        col[pos] = dst[e];
        wgt[pos] = w[e];
    }
}

// ---------------- helpers ----------------

__device__ __forceinline__ u16 f2bf(float f) {
    __hip_bfloat16 b = __float2bfloat16(f);            // RNE
    return *reinterpret_cast<u16*>(&b);
}
__device__ __forceinline__ float bflo(u32 d) { return __uint_as_float(d << 16); }
__device__ __forceinline__ float bfhi(u32 d) { return __uint_as_float(d & 0xffff0000u); }

// ---------------- W -> bf16, transposed for MFMA B-frags: WbfT[g][416] ----------------

__global__ void prep_wbf(const float* __restrict__ W, u16* __restrict__ WbfT) {
    int t = blockIdx.x * 256 + threadIdx.x;   // t over 64*416
    if (t >= GG * 416) return;
    int g = t / 416;
    int f = t % 416;
    int k = f >> 4;
    int h = f & 15;
    float v = (k < KK && h < HH) ? W[(k * HH + h) * GG + g] : 0.f;
    WbfT[(size_t)g * 416 + f] = f2bf(v);
}

// ---------------- transpose chunk: packed bf16 rows [n][bb][h-pairs] ----------------

template<int BCH>
__global__ void transpose_bf(const float* __restrict__ x, u32* __restrict__ X0, int b0) {
    constexpr int CW = BCH * 8;
    int t = blockIdx.x * 256 + threadIdx.x;     // t = n*CW + j
    int n = t / CW;
    int j = t % CW;
    int bb = j >> 3;
    int h0 = (j & 7) * 2;
    const float* xb = x + ((size_t)(b0 + bb) * NN + n) * HH;
    float lo = xb[h0];
    float hi = (h0 + 1 < HH) ? xb[h0 + 1] : 0.f;
    X0[t] = (u32)f2bf(lo) | ((u32)f2bf(hi) << 16);
}

// ---------------- SPMM (BCH==32): block per row, wave per 256B quarter-row ----------------
// lane = (grp = edge slot 0..3, m16 = dword-quad 0..15); 2-deep pipeline (8 edges/iter).

__global__ __launch_bounds__(256) void spmm_bf32(
    const int* __restrict__ rowptr, const int* __restrict__ col, const float* __restrict__ wgt,
    const u32* __restrict__ Xin, const u32* __restrict__ Xprev, u32* __restrict__ Xout,
    float alpha, float beta)
{
    int qc   = threadIdx.x >> 6;   // quarter 0..3
    int lane = threadIdx.x & 63;
    int n = blockIdx.x;
    int e0 = rowptr[n], e1 = rowptr[n + 1];
    int grp = lane >> 4;
    int m16 = lane & 15;
    const u32* xq = Xin + (size_t)qc * 64 + (size_t)m16 * 4;

    float al[4] = {0.f,0.f,0.f,0.f}, ah[4] = {0.f,0.f,0.f,0.f};
    float bl[4] = {0.f,0.f,0.f,0.f}, bh[4] = {0.f,0.f,0.f,0.f};

    for (int base = e0; base < e1; base += 64) {
        int cnt = e1 - base;
        if (cnt > 64) cnt = 64;
        int cv = 0; float wv = 0.f;
        if (lane < cnt) { cv = col[base + lane]; wv = wgt[base + lane]; }
        int j = 0;
        for (; j + 8 <= cnt; j += 8) {
            int   iA = __shfl(cv, j + grp);
            float wA = __shfl(wv, j + grp);
            int   iB = __shfl(cv, j + 4 + grp);
            float wB = __shfl(wv, j + 4 + grp);
            u32x4 dA = *(const u32x4*)(xq + (size_t)iA * 256);
            u32x4 dB = *(const u32x4*)(xq + (size_t)iB * 256);
#pragma unroll
            for (int i = 0; i < 4; ++i) {
                al[i] = fmaf(wA, bflo(dA[i]), al[i]);
                ah[i] = fmaf(wA, bfhi(dA[i]), ah[i]);
                bl[i] = fmaf(wB, bflo(dB[i]), bl[i]);
                bh[i] = fmaf(wB, bfhi(dB[i]), bh[i]);
            }
        }
        for (; j < cnt; j += 4) {
            int   iA = __shfl(cv, j + grp);
            float wA = __shfl(wv, j + grp);
            u32x4 dA = *(const u32x4*)(xq + (size_t)iA * 256);
#pragma unroll
            for (int i = 0; i < 4; ++i) {
                al[i] = fmaf(wA, bflo(dA[i]), al[i]);
                ah[i] = fmaf(wA, bfhi(dA[i]), ah[i]);
            }
        }
    }

#pragma unroll
    for (int i = 0; i < 4; ++i) { al[i] += bl[i]; ah[i] += bh[i]; }
#pragma unroll
    for (int off = 16; off < 64; off <<= 1)
#pragma unroll
        for (int i = 0; i < 4; ++i) {
            al[i] += __shfl_xor(al[i], off);
            ah[i] += __shfl_xor(ah[i], off);
        }

    if (grp == 0) {
        size_t o = (size_t)n * 256 + (size_t)qc * 64 + (size_t)m16 * 4;
        u32x4 dp = {0,0,0,0};
        if (beta != 0.f) dp = *(const u32x4*)(Xprev + o);
        u32x4 r;
#pragma unroll
        for (int i = 0; i < 4; ++i) {
            float rl = alpha * al[i];
            float rh = alpha * ah[i];
            if (beta != 0.f) {
                rl = fmaf(beta, bflo(dp[i]), rl);
                rh = fmaf(beta, bfhi(dp[i]), rh);
            }
            r[i] = (u32)f2bf(rl) | ((u32)f2bf(rh) << 16);
        }
        *(u32x4*)(Xout + o) = r;
    }
}

// ---------------- SPMM quad-gather (BCH==8), 2-deep (R7 proven) ----------------

__global__ __launch_bounds__(256) void spmm_bf8(
    const int* __restrict__ rowptr, const int* __restrict__ col, const float* __restrict__ wgt,
    const u32* __restrict__ Xin, const u32* __restrict__ Xprev, u32* __restrict__ Xout,
    float alpha, float beta)
{
    int sub  = threadIdx.x >> 6;
    int lane = threadIdx.x & 63;
    int n = blockIdx.x * 4 + sub;
    int e0 = rowptr[n], e1 = rowptr[n + 1];
    int grp = lane >> 4;
    int m16 = lane & 15;

    float al[4] = {0.f,0.f,0.f,0.f}, ah[4] = {0.f,0.f,0.f,0.f};
    float bl[4] = {0.f,0.f,0.f,0.f}, bh[4] = {0.f,0.f,0.f,0.f};

    for (int base = e0; base < e1; base += 64) {
        int cnt = e1 - base;
        if (cnt > 64) cnt = 64;
        int cv = 0; float wv = 0.f;
        if (lane < cnt) { cv = col[base + lane]; wv = wgt[base + lane]; }
        int j = 0;
        for (; j + 8 <= cnt; j += 8) {
            int   iA = __shfl(cv, j + grp);
            float wA = __shfl(wv, j + grp);
            int   iB = __shfl(cv, j + 4 + grp);
            float wB = __shfl(wv, j + 4 + grp);
            u32x4 dA = *(const u32x4*)(Xin + (size_t)iA * 64 + m16 * 4);
            u32x4 dB = *(const u32x4*)(Xin + (size_t)iB * 64 + m16 * 4);
#pragma unroll
            for (int i = 0; i < 4; ++i) {
                al[i] = fmaf(wA, bflo(dA[i]), al[i]);
                ah[i] = fmaf(wA, bfhi(dA[i]), ah[i]);
                bl[i] = fmaf(wB, bflo(dB[i]), bl[i]);
                bh[i] = fmaf(wB, bfhi(dB[i]), bh[i]);
            }
        }
        for (; j < cnt; j += 4) {
            int   iA = __shfl(cv, j + grp);
            float wA = __shfl(wv, j + grp);
            u32x4 dA = *(const u32x4*)(Xin + (size_t)iA * 64 + m16 * 4);
#pragma unroll
            for (int i = 0; i < 4; ++i) {
                al[i] = fmaf(wA, bflo(dA[i]), al[i]);
                ah[i] = fmaf(wA, bfhi(dA[i]), ah[i]);
            }
        }
    }

#pragma unroll
    for (int i = 0; i < 4; ++i) { al[i] += bl[i]; ah[i] += bh[i]; }
#pragma unroll
    for (int off = 16; off < 64; off <<= 1)
#pragma unroll
        for (int i = 0; i < 4; ++i) {
            al[i] += __shfl_xor(al[i], off);
            ah[i] += __shfl_xor(ah[i], off);
        }

    if (grp == 0) {
        size_t o = (size_t)n * 64 + (size_t)m16 * 4;
        u32x4 dp = {0,0,0,0};
        if (beta != 0.f) dp = *(const u32x4*)(Xprev + o);
        u32x4 r;
#pragma unroll
        for (int i = 0; i < 4; ++i) {
            float rl = alpha * al[i];
            float rh = alpha * ah[i];
            if (beta != 0.f) {
                rl = fmaf(beta, bflo(dp[i]), rl);
                rh = fmaf(beta, bfhi(dp[i]), rh);
            }
            r[i] = (u32)f2bf(rl) | ((u32)f2bf(rh) << 16);
        }
        *(u32x4*)(Xout + o) = r;
    }
}

// ---------------- SPMM quad-gather (BCH==4) ----------------

__global__ __launch_bounds__(256) void spmm_bf4(
    const int* __restrict__ rowptr, const int* __restrict__ col, const float* __restrict__ wgt,
    const u32* __restrict__ Xin, const u32* __restrict__ Xprev, u32* __restrict__ Xout,
    float alpha, float beta)
{
    int sub  = threadIdx.x >> 6;
    int lane = threadIdx.x & 63;
    int n = blockIdx.x * 4 + sub;
    int e0 = rowptr[n], e1 = rowptr[n + 1];
    int grp = lane >> 3;
    int m8  = lane & 7;

    float al[4] = {0.f,0.f,0.f,0.f}, ah[4] = {0.f,0.f,0.f,0.f};
    float bl[4] = {0.f,0.f,0.f,0.f}, bh[4] = {0.f,0.f,0.f,0.f};

    for (int base = e0; base < e1; base += 64) {
        int cnt = e1 - base;
        if (cnt > 64) cnt = 64;
        int cv = 0; float wv = 0.f;
        if (lane < cnt) { cv = col[base + lane]; wv = wgt[base + lane]; }
        int j = 0;
        for (; j + 16 <= cnt; j += 16) {
            int   iA = __shfl(cv, j + grp);
            float wA = __shfl(wv, j + grp);
            int   iB = __shfl(cv, j + 8 + grp);
            float wB = __shfl(wv, j + 8 + grp);
            u32x4 dA = *(const u32x4*)(Xin + (size_t)iA * 32 + m8 * 4);
            u32x4 dB = *(const u32x4*)(Xin + (size_t)iB * 32 + m8 * 4);
#pragma unroll
            for (int i = 0; i < 4; ++i) {
                al[i] = fmaf(wA, bflo(dA[i]), al[i]);
                ah[i] = fmaf(wA, bfhi(dA[i]), ah[i]);
                bl[i] = fmaf(wB, bflo(dB[i]), bl[i]);
                bh[i] = fmaf(wB, bfhi(dB[i]), bh[i]);
            }
        }
        for (; j < cnt; j += 8) {
            int   iA = __shfl(cv, j + grp);
            float wA = __shfl(wv, j + grp);
            u32x4 dA = *(const u32x4*)(Xin + (size_t)iA * 32 + m8 * 4);
#pragma unroll
            for (int i = 0; i < 4; ++i) {
                al[i] = fmaf(wA, bflo(dA[i]), al[i]);
                ah[i] = fmaf(wA, bfhi(dA[i]), ah[i]);
            }
        }
    }

#pragma unroll
    for (int i = 0; i < 4; ++i) { al[i] += bl[i]; ah[i] += bh[i]; }
#pragma unroll
    for (int off = 8; off < 64; off <<= 1)
#pragma unroll
        for (int i = 0; i < 4; ++i) {
            al[i] += __shfl_xor(al[i], off);
            ah[i] += __shfl_xor(ah[i], off);
        }

    if (grp == 0) {
        size_t o = (size_t)n * 32 + (size_t)m8 * 4;
        u32x4 dp = {0,0,0,0};
        if (beta != 0.f) dp = *(const u32x4*)(Xprev + o);
        u32x4 r;
#pragma unroll
        for (int i = 0; i < 4; ++i) {
            float rl = alpha * al[i];
            float rh = alpha * ah[i];
            if (beta != 0.f) {
                rl = fmaf(beta, bflo(dp[i]), rl);
                rh = fmaf(beta, bfhi(dp[i]), rh);
            }
            r[i] = (u32)f2bf(rl) | ((u32)f2bf(rh) << 16);
        }
        *(u32x4*)(Xout + o) = r;
    }
}

// ---------------- SPMM scalar fallback (BCH<4) ----------------

template<int BCH>
__global__ __launch_bounds__(256) void spmm_bf(
    const int* __restrict__ rowptr, const int* __restrict__ col, const float* __restrict__ wgt,
    const u32* __restrict__ Xin, const u32* __restrict__ Xprev, u32* __restrict__ Xout,
    float alpha, float beta)
{
    constexpr int C  = BCH * 16;
    int sub  = threadIdx.x >> 6;
    int lane = threadIdx.x & 63;
    int n = blockIdx.x * 4 + sub;
    int e0 = rowptr[n], e1 = rowptr[n + 1];

    int c = lane;
    const u16* XinU  = (const u16*)Xin;
    const u16* XprevU= (const u16*)Xprev;
    u16* XoutU = (u16*)Xout;
    float a0=0.f,a1=0.f,a2=0.f,a3=0.f;
    bool act = (c < C);
    for (int base = e0; base < e1; base += 64) {
        int cnt = e1 - base;
        if (cnt > 64) cnt = 64;
        int cv = 0; float wv = 0.f;
        if (lane < cnt) { cv = col[base + lane]; wv = wgt[base + lane]; }
        int j = 0;
        for (; j + 4 <= cnt; j += 4) {
            int i0 = __builtin_amdgcn_readlane(cv, j);
            int i1 = __builtin_amdgcn_readlane(cv, j + 1);
            int i2 = __builtin_amdgcn_readlane(cv, j + 2);
            int i3 = __builtin_amdgcn_readlane(cv, j + 3);
            float w0 = __int_as_float(__builtin_amdgcn_readlane(__float_as_int(wv), j));
            float w1 = __int_as_float(__builtin_amdgcn_readlane(__float_as_int(wv), j + 1));
            float w2 = __int_as_float(__builtin_amdgcn_readlane(__float_as_int(wv), j + 2));
            float w3 = __int_as_float(__builtin_amdgcn_readlane(__float_as_int(wv), j + 3));
            if (act) {
                float x0 = __uint_as_float((u32)XinU[(size_t)i0 * C + c] << 16);
                float x1 = __uint_as_float((u32)XinU[(size_t)i1 * C + c] << 16);
                float x2 = __uint_as_float((u32)XinU[(size_t)i2 * C + c] << 16);
                float x3 = __uint_as_float((u32)XinU[(size_t)i3 * C + c] << 16);
                a0 = fmaf(w0, x0, a0);
                a1 = fmaf(w1, x1, a1);
                a2 = fmaf(w2, x2, a2);
                a3 = fmaf(w3, x3, a3);
            }
        }
        for (; j < cnt; ++j) {
            int i0 = __builtin_amdgcn_readlane(cv, j);
            float w0 = __int_as_float(__builtin_amdgcn_readlane(__float_as_int(wv), j));
            if (act) a0 = fmaf(w0, __uint_as_float((u32)XinU[(size_t)i0 * C + c] << 16), a0);
        }
    }
    if (act) {
        float r = alpha * ((a0 + a1) + (a2 + a3));
        size_t o = (size_t)n * C + c;
        if (beta != 0.f)
            r = fmaf(beta, __uint_as_float((u32)XprevU[o] << 16), r);
        XoutU[o] = f2bf(r);
    }
}

// ---------------- final4_32: MFMA contraction, single pass (BCH==32) ----------------
// rows r = n*32 + bb; block = 64 rows = 2 nodes; 8192 blocks.

__global__ __launch_bounds__(256) void final4_32(
    const u32* __restrict__ Xall, const u16* __restrict__ WbfT,
    const float* __restrict__ b_conv, const float* __restrict__ Wfc,
    float* __restrict__ partials)
{
    constexpr int SLICE_DW = NN * 256;
    __shared__ float sred[2][32 * CC];
    int tid  = threadIdx.x;
    int wid  = tid >> 6;
    int lane = tid & 63;
    int q = lane >> 4;
    int m = lane & 15;
    int r0 = (blockIdx.x * 4 + wid) * 16;
    int r  = r0 + m;

    f32x4 acc0 = {0.f,0.f,0.f,0.f}, acc1 = {0.f,0.f,0.f,0.f};
    f32x4 acc2 = {0.f,0.f,0.f,0.f}, acc3 = {0.f,0.f,0.f,0.f};

    const u32* abase = Xall + (size_t)r * 8 + (size_t)(q & 1) * 4;
    const u16* bbase = WbfT + (size_t)m * 416 + q * 8;

#pragma unroll
    for (int s = 0; s < 13; ++s) {
        int ks = 2 * s + (q >> 1);
        bf16x8 af = {0,0,0,0,0,0,0,0};
        if (s < 12 || q < 2)
            af = *(const bf16x8*)(abase + (size_t)ks * SLICE_DW);
        bf16x8 bf0 = *(const bf16x8*)(bbase + (size_t)0 * 16 * 416 + s * 32);
        bf16x8 bf1 = *(const bf16x8*)(bbase + (size_t)1 * 16 * 416 + s * 32);
        bf16x8 bf2 = *(const bf16x8*)(bbase + (size_t)2 * 16 * 416 + s * 32);
        bf16x8 bf3 = *(const bf16x8*)(bbase + (size_t)3 * 16 * 416 + s * 32);
        acc0 = __builtin_amdgcn_mfma_f32_16x16x32_bf16(af, bf0, acc0, 0, 0, 0);
        acc1 = __builtin_amdgcn_mfma_f32_16x16x32_bf16(af, bf1, acc1, 0, 0, 0);
        acc2 = __builtin_amdgcn_mfma_f32_16x16x32_bf16(af, bf2, acc2, 0, 0, 0);
        acc3 = __builtin_amdgcn_mfma_f32_16x16x32_bf16(af, bf3, acc3, 0, 0, 0);
    }

    float part[4][CC];
#pragma unroll
    for (int i = 0; i < 4; ++i)
#pragma unroll
        for (int c = 0; c < CC; ++c) part[i][c] = 0.f;

#pragma unroll
    for (int gt = 0; gt < 4; ++gt) {
        f32x4 a = (gt == 0) ? acc0 : (gt == 1) ? acc1 : (gt == 2) ? acc2 : acc3;
        float bias = b_conv[gt * 16 + m];
#pragma unroll
        for (int i = 0; i < 4; ++i) {
            int rr = r0 + q * 4 + i;
            int nrow = rr >> 5;
            float hv = fmaxf(a[i] + bias, 0.f);
#pragma unroll
            for (int c = 0; c < CC; ++c)
                part[i][c] = fmaf(hv,
                    Wfc[(size_t)c * NG + (size_t)nrow * GG + gt * 16 + m], part[i][c]);
        }
    }

    // reduce over m (g dim); each (q,i) is a distinct bb of one node
#pragma unroll
    for (int o = 1; o < 16; o <<= 1)
#pragma unroll
        for (int i = 0; i < 4; ++i)
#pragma unroll
            for (int c = 0; c < CC; ++c)
                part[i][c] += __shfl_xor(part[i][c], o);

    if (m == 0) {
        int node = wid >> 1;
        int bbb  = (wid & 1) * 16;
#pragma unroll
        for (int i = 0; i < 4; ++i)
#pragma unroll
            for (int c = 0; c < CC; ++c)
                sred[node][(bbb + q * 4 + i) * CC + c] = part[i][c];
    }
    __syncthreads();
    if (tid < 32 * CC) {
        float s2 = sred[0][tid] + sred[1][tid];
        int bb = tid / CC;
        int c  = tid % CC;
        partials[((size_t)bb * CC + c) * PSTRIDE + blockIdx.x] = s2;
    }
}

// ---------------- final4: MFMA contraction (BCH == 8 or 4) ----------------

template<int BCH>
__global__ __launch_bounds__(256) void final4_t(
    const u32* __restrict__ Xall, const u16* __restrict__ WbfT,
    const float* __restrict__ b_conv, const float* __restrict__ Wfc,
    float* __restrict__ partials, int b0)
{
    constexpr int SLICE_DW = NN * BCH * 8;
    __shared__ float sred[4][BCH * CC];
    int tid  = threadIdx.x;
    int wid  = tid >> 6;
    int lane = tid & 63;
    int q = lane >> 4;
    int m = lane & 15;
    int r0 = (blockIdx.x * 4 + wid) * 16;
    int r  = r0 + m;

    f32x4 acc0 = {0.f,0.f,0.f,0.f}, acc1 = {0.f,0.f,0.f,0.f};
    f32x4 acc2 = {0.f,0.f,0.f,0.f}, acc3 = {0.f,0.f,0.f,0.f};

    const u32* abase = Xall + (size_t)r * 8 + (size_t)(q & 1) * 4;
    const u16* bbase = WbfT + (size_t)m * 416 + q * 8;

#pragma unroll
    for (int s = 0; s < 13; ++s) {
        int ks = 2 * s + (q >> 1);
        bf16x8 af = {0,0,0,0,0,0,0,0};
        if (s < 12 || q < 2)
            af = *(const bf16x8*)(abase + (size_t)ks * SLICE_DW);
        bf16x8 bf0 = *(const bf16x8*)(bbase + (size_t)0 * 16 * 416 + s * 32);
        bf16x8 bf1 = *(const bf16x8*)(bbase + (size_t)1 * 16 * 416 + s * 32);
        bf16x8 bf2 = *(const bf16x8*)(bbase + (size_t)2 * 16 * 416 + s * 32);
        bf16x8 bf3 = *(const bf16x8*)(bbase + (size_t)3 * 16 * 416 + s * 32);
        acc0 = __builtin_amdgcn_mfma_f32_16x16x32_bf16(af, bf0, acc0, 0, 0, 0);
        acc1 = __builtin_amdgcn_mfma_f32_16x16x32_bf16(af, bf1, acc1, 0, 0, 0);
        acc2 = __builtin_amdgcn_mfma_f32_16x16x32_bf16(af, bf2, acc2, 0, 0, 0);
        acc3 = __builtin_amdgcn_mfma_f32_16x16x32_bf16(af, bf3, acc3, 0, 0, 0);
    }

    float part[4][CC];
#pragma unroll
    for (int i = 0; i < 4; ++i)
#pragma unroll
        for (int c = 0; c < CC; ++c) part[i][c] = 0.f;

#pragma unroll
    for (int gt = 0; gt < 4; ++gt) {
        f32x4 a = (gt == 0) ? acc0 : (gt == 1) ? acc1 : (gt == 2) ? acc2 : acc3;
        float bias = b_conv[gt * 16 + m];
#pragma unroll
        for (int i = 0; i < 4; ++i) {
            int rr = r0 + q * 4 + i;
            int nrow = rr / BCH;
            float hv = fmaxf(a[i] + bias, 0.f);
#pragma unroll
            for (int c = 0; c < CC; ++c)
                part[i][c] = fmaf(hv,
                    Wfc[(size_t)c * NG + (size_t)nrow * GG + gt * 16 + m], part[i][c]);
        }
    }

#pragma unroll
    for (int o = 1; o < 16; o <<= 1)
#pragma unroll
        for (int i = 0; i < 4; ++i)
#pragma unroll
            for (int c = 0; c < CC; ++c)
                part[i][c] += __shfl_xor(part[i][c], o);

    if constexpr (BCH == 8) {
#pragma unroll
        for (int i = 0; i < 4; ++i)
#pragma unroll
            for (int c = 0; c < CC; ++c)
                part[i][c] += __shfl_xor(part[i][c], 32);
        if (m == 0 && q < 2) {
#pragma unroll
            for (int i = 0; i < 4; ++i)
#pragma unroll
                for (int c = 0; c < CC; ++c)
                    sred[wid][(q * 4 + i) * CC + c] = part[i][c];
        }
    } else {
#pragma unroll
        for (int o = 16; o < 64; o <<= 1)
#pragma unroll
            for (int i = 0; i < 4; ++i)
#pragma unroll
                for (int c = 0; c < CC; ++c)
                    part[i][c] += __shfl_xor(part[i][c], o);
        if (lane == 0) {
#pragma unroll
            for (int i = 0; i < 4; ++i)
#pragma unroll
                for (int c = 0; c < CC; ++c)
                    sred[wid][i * CC + c] = part[i][c];
        }
    }
    __syncthreads();
    if (tid < BCH * CC) {
        float s4 = sred[0][tid] + sred[1][tid] + sred[2][tid] + sred[3][tid];
        int bb = tid / CC;
        int c  = tid % CC;
        partials[((size_t)(b0 + bb) * CC + c) * PSTRIDE + blockIdx.x] = s4;
    }
}

// ---------------- final3 (fallback for BCH<4) ----------------

template<int BCH>
__global__ __launch_bounds__(256) void final3_t(
    const u32* __restrict__ Xall, const float* __restrict__ W,
    const float* __restrict__ b_conv, const float* __restrict__ Wfc,
    float* __restrict__ partials, int b0)
{
    constexpr int CW = BCH * 8;
    __shared__ float sred[4][BCH * CC];
    int g   = threadIdx.x & 63;
    int nlu = __builtin_amdgcn_readfirstlane((int)threadIdx.x) >> 6;
    int n   = blockIdx.x * 4 + nlu;

    float acc[BCH];
#pragma unroll
    for (int bb = 0; bb < BCH; ++bb) acc[bb] = 0.f;

    for (int k = 0; k < KK; ++k) {
        const u32* __restrict__ xrow = Xall + ((size_t)k * NN + n) * CW;
        const float* __restrict__ Wk = W + k * (HH * GG);
        float wreg[HH];
#pragma unroll
        for (int h = 0; h < HH; ++h) wreg[h] = Wk[h * GG + g];
#pragma unroll
        for (int bb = 0; bb < BCH; ++bb) {
            float a = acc[bb];
#pragma unroll
            for (int p = 0; p < 8; ++p) {
                u32 d = xrow[bb * 8 + p];
                a = fmaf(bflo(d), wreg[2 * p], a);
                if (p < 7) a = fmaf(bfhi(d), wreg[2 * p + 1], a);
            }
            acc[bb] = a;
        }
    }

    float bias = b_conv[g];
    float wv[CC];
#pragma unroll
    for (int c = 0; c < CC; ++c)
        wv[c] = Wfc[(size_t)c * NG + (size_t)n * GG + g];

#pragma unroll
    for (int bb = 0; bb < BCH; ++bb) {
        float hv = fmaxf(acc[bb] + bias, 0.f);
#pragma unroll
        for (int c = 0; c < CC; ++c) {
            float s = hv * wv[c];
#pragma unroll
            for (int off = 1; off < 64; off <<= 1) s += __shfl_xor(s, off);
            if (g == 0) sred[nlu][bb * CC + c] = s;
        }
    }
    __syncthreads();
    if (threadIdx.x < BCH * CC) {
        float s = sred[0][threadIdx.x] + sred[1][threadIdx.x]
                + sred[2][threadIdx.x] + sred[3][threadIdx.x];
        int bb = threadIdx.x / CC;
        int c  = threadIdx.x % CC;
        partials[((size_t)(b0 + bb) * CC + c) * PSTRIDE + blockIdx.x] = s;
    }
}

// ---------------- partials -> logits ----------------

__global__ __launch_bounds__(256) void reduce_logits(const float* __restrict__ partials,
                                                     float* __restrict__ logits, int nblk) {
    int idx = blockIdx.x;   // b*CC + c
    const float* p = partials + (size_t)idx * PSTRIDE;
    float s = 0.f;
    for (int i = threadIdx.x; i < nblk; i += 256) s += p[i];
#pragma unroll
    for (int off = 1; off < 64; off <<= 1) s += __shfl_xor(s, off);
    __shared__ float sr[4];
    if ((threadIdx.x & 63) == 0) sr[threadIdx.x >> 6] = s;
    __syncthreads();
    if (threadIdx.x == 0) logits[idx] = sr[0] + sr[1] + sr[2] + sr[3];
}

// ---------------- log_softmax ----------------

__global__ void lsm_kernel(const float* __restrict__ logits, const float* __restrict__ b_fc,
                           float* __restrict__ out) {
    int b = threadIdx.x;
    if (b >= BB) return;
    float v[CC];
    float m = -1e30f;
#pragma unroll
    for (int c = 0; c < CC; ++c) {
        v[c] = logits[b * CC + c] + b_fc[c];
        m = fmaxf(m, v[c]);
    }
    float s = 0.f;
#pragma unroll
    for (int c = 0; c < CC; ++c) s += expf(v[c] - m);
    float ls = m + logf(s);
#pragma unroll
    for (int c = 0; c < CC; ++c) out[b * CC + c] = v[c] - ls;
}

__global__ void sentinel_kernel(float* __restrict__ out) {
    int t = threadIdx.x;
    if (t < BB * CC) out[t] = -12345.f;
}

// ---------------- per-tier pass driver ----------------

template<int BCH>
static void run_passes(const float* x, const float* W, const u16* WbfT,
                       const float* bconv, const float* Wfc,
                       const int* rowptr, const int* col, const float* wgt,
                       u32* Xall, float* partials, hipStream_t stream)
{
    constexpr int CW = BCH * 8;
    const size_t slice = (size_t)NN * CW;   // dwords per slice

    for (int p = 0; p < BB / BCH; ++p) {
        int b0 = p * BCH;
        transpose_bf<BCH><<<(NN * CW) / 256, 256, 0, stream>>>(x, Xall, b0);
        if constexpr (BCH == 32) {
            spmm_bf32<<<NN, 256, 0, stream>>>(
                rowptr, col, wgt, Xall, Xall, Xall + slice, 1.f, 0.f);
            for (int k = 2; k < KK; ++k) {
                spmm_bf32<<<NN, 256, 0, stream>>>(
                    rowptr, col, wgt,
                    Xall + (size_t)(k - 1) * slice,
                    Xall + (size_t)(k - 2) * slice,
                    Xall + (size_t)k * slice, 2.f, -1.f);
            }
            final4_32<<<NN * 32 / 64, 256, 0, stream>>>(Xall, WbfT, bconv, Wfc, partials);
        } else if constexpr (BCH == 8) {
            spmm_bf8<<<NN / 4, 256, 0, stream>>>(
                rowptr, col, wgt, Xall, Xall, Xall + slice, 1.f, 0.f);
            for (int k = 2; k < KK; ++k) {
                spmm_bf8<<<NN / 4, 256, 0, stream>>>(
                    rowptr, col, wgt,
                    Xall + (size_t)(k - 1) * slice,
                    Xall + (size_t)(k - 2) * slice,
                    Xall + (size_t)k * slice, 2.f, -1.f);
            }
            final4_t<8><<<NN * 8 / 64, 256, 0, stream>>>(Xall, WbfT, bconv, Wfc, partials, b0);
        } else if constexpr (BCH == 4) {
            spmm_bf4<<<NN / 4, 256, 0, stream>>>(
                rowptr, col, wgt, Xall, Xall, Xall + slice, 1.f, 0.f);
            for (int k = 2; k < KK; ++k) {
                spmm_bf4<<<NN / 4, 256, 0, stream>>>(
                    rowptr, col, wgt,
                    Xall + (size_t)(k - 1) * slice,
                    Xall + (size_t)(k - 2) * slice,
                    Xall + (size_t)k * slice, 2.f, -1.f);
            }
            final4_t<4><<<NN * 4 / 64, 256, 0, stream>>>(Xall, WbfT, bconv, Wfc, partials, b0);
        } else {
            spmm_bf<BCH><<<NN / 4, 256, 0, stream>>>(
                rowptr, col, wgt, Xall, Xall, Xall + slice, 1.f, 0.f);
            for (int k = 2; k < KK; ++k) {
                spmm_bf<BCH><<<NN / 4, 256, 0, stream>>>(
                    rowptr, col, wgt,
                    Xall + (size_t)(k - 1) * slice,
                    Xall + (size_t)(k - 2) * slice,
                    Xall + (size_t)k * slice, 2.f, -1.f);
            }
            final3_t<BCH><<<NN / 4, 256, 0, stream>>>(Xall, W, bconv, Wfc, partials, b0);
        }
    }
}

// ---------------- launch ----------------

extern "C" void kernel_launch(void* const* d_in, const int* in_sizes, int n_in,
                              void* d_out, int out_size, void* d_ws, size_t ws_size,
                              hipStream_t stream) {
    const float* x     = (const float*)d_in[0];
    const float* ew    = (const float*)d_in[1];
    const float* W     = (const float*)d_in[2];
    const float* bconv = (const float*)d_in[3];
    const float* Wfc   = (const float*)d_in[4];
    const float* bfc   = (const float*)d_in[5];
    const int*   esrc  = (const int*)d_in[6];
    const int*   edst  = (const int*)d_in[7];
    float* out = (float*)d_out;

    char* ws = (char*)d_ws;
    size_t off = 0;
    auto alloc = [&](size_t bytes) -> void* {
        void* p = (void*)(ws + off);
        off = (off + bytes + 255) & ~(size_t)255;
        return p;
    };
    int*   rowptr   = (int*)  alloc((size_t)(NN + 1) * 4);
    int*   cursor   = (int*)  alloc((size_t)NN * 4);
    int*   cnt      = (int*)  alloc((size_t)NN * 4);
    int*   col      = (int*)  alloc((size_t)EE * 4);
    float* wgt      = (float*)alloc((size_t)EE * 4);
    float* logits   = (float*)alloc(256 * 4);
    u16*   WbfT     = (u16*)  alloc((size_t)GG * 416 * 2);
    float* partials = (float*)alloc((size_t)BB * CC * PSTRIDE * 4);
    size_t fixed = off;

    int BCH = 0;
    for (int b = 32; b >= 1; b >>= 1) {
        size_t need = fixed + (size_t)KK * NN * (size_t)b * 16 * 2;   // bf16 slices
        if (need <= ws_size) { BCH = b; break; }
        if (b == 32) b = 16;   // next tier down is 8 (16 not implemented); harmless halving
    }
    if (BCH == 16) BCH = 8;
    if (BCH == 0) {
        sentinel_kernel<<<1, 256, 0, stream>>>(out);
        return;
    }
    u32* Xall = (u32*)(ws + fixed);

    init_counts<<<(NN + 255) / 256, 256, 0, stream>>>(cnt);
    hist_kernel<<<(EE + 255) / 256, 256, 0, stream>>>(esrc, cnt);
    scan_kernel<<<1, 1024, 0, stream>>>(cnt, rowptr, cursor);
    scatter_kernel<<<(EE + 255) / 256, 256, 0, stream>>>(esrc, edst, ew, cursor, col, wgt);
    prep_wbf<<<(GG * 416 + 255) / 256, 256, 0, stream>>>(W, WbfT);

    switch (BCH) {
        case 32: run_passes<32>(x, W, WbfT, bconv, Wfc, rowptr, col, wgt, Xall, partials, stream); break;
        case 8:  run_passes<8>(x, W, WbfT, bconv, Wfc, rowptr, col, wgt, Xall, partials, stream); break;
        case 4:  run_passes<4>(x, W, WbfT, bconv, Wfc, rowptr, col, wgt, Xall, partials, stream); break;
        case 2:  run_passes<2>(x, W, WbfT, bconv, Wfc, rowptr, col, wgt, Xall, partials, stream); break;
        default: run_passes<1>(x, W, WbfT, bconv, Wfc, rowptr, col, wgt, Xall, partials, stream); break;
    }

    int nblk = (BCH == 32) ? 8192 : (BCH == 8) ? 2048 : (BCH == 4) ? 1024 : (NN / 4);
    reduce_logits<<<BB * CC, 256, 0, stream>>>(partials, logits, nblk);
    lsm_kernel<<<1, 64, 0, stream>>>(logits, bfc, out);
}